// Round 4
// baseline (753.450 us; speedup 1.0000x reference)
//
#include <hip/hip_runtime.h>
#include <math.h>

#define PH 7
#define PW 7

// ---- exact integer emulation of fast-math f32: bin = roi * RN(1/7) ----
// RN_f32(1/7) = 9586981 * 2^-26  (2^26/7 = 9586980.571 -> RNE 9586981)
#define C7 9586981LL

// round a non-negative int64 to 24 significant bits, round-to-nearest-even
// (this IS the f32 RN of the product, expressed on the integer significand)
__device__ __forceinline__ long long round24(long long v) {
    if (v == 0) return 0;
    int L = 64 - __clzll((unsigned long long)v);
    int sh = L - 24;
    if (sh <= 0) return v;
    long long rem  = v & ((1LL << sh) - 1);
    long long base = v >> sh;
    long long half = 1LL << (sh - 1);
    if (rem > half || (rem == half && (base & 1))) base++;
    return base << sh;
}

// bin' = RN_f32(roi * RN_f32(1/7)), exact at scale 2^-26
__device__ __forceinline__ long long bin_q26(int roi) {
    return round24((long long)roi * C7);
}
// floorf(RN_f32(k * bin')) and ceilf(RN_f32(k * bin'))
__device__ __forceinline__ int floor_k(long long b26, int k) {
    long long v = round24((long long)k * b26);   // the f32 multiply
    return (int)(v >> 26);
}
__device__ __forceinline__ int ceil_k(long long b26, int k) {
    long long v = round24((long long)k * b26);
    return (int)((v + ((1LL << 26) - 1)) >> 26);
}

// features: (4, 512, 64, 64) f32 | rois: (2000, 5) f32 | out: (2000, 512, 7, 7) f32
__global__ void roipool_kernel(const float* __restrict__ features,
                               const float* __restrict__ rois,
                               float* __restrict__ out,
                               int total) {
    const int C = 512, H = 64, W = 64;
    int idx = blockIdx.x * blockDim.x + threadIdx.x;
    if (idx >= total) return;

    int pw = idx % PW;
    int ph = (idx / PW) % PH;
    int c  = (idx / (PW * PH)) % C;
    int r  = idx / (PW * PH * C);

    const float* roi = rois + r * 5;
    int b  = (int)roi[0];                    // astype(int32) = trunc
    int x1 = (int)rintf(roi[1] * 0.0625f);   // exact mult (2^-4); RNE = jnp.round
    int y1 = (int)rintf(roi[2] * 0.0625f);
    int x2 = (int)rintf(roi[3] * 0.0625f);
    int y2 = (int)rintf(roi[4] * 0.0625f);

    int roi_w = max(x2 - x1 + 1, 1);         // 1..65
    int roi_h = max(y2 - y1 + 1, 1);

    long long bh = bin_q26(roi_h);
    long long bw = bin_q26(roi_w);

    int hstart = y1 + floor_k(bh, ph);
    int hend   = y1 + ceil_k (bh, ph + 1);
    int wstart = x1 + floor_k(bw, pw);
    int wend   = x1 + ceil_k (bw, pw + 1);

    hstart = min(max(hstart, 0), H);
    hend   = min(max(hend,   0), H);
    wstart = min(max(wstart, 0), W);
    wend   = min(max(wend,   0), W);

    bool empty = (hend <= hstart) || (wend <= wstart);

    const float* fmap = features + ((size_t)b * C + c) * (size_t)(H * W);
    float m = -3.402823466e+38f;   // -FLT_MAX (no inf: fast-math safe)
    for (int h = hstart; h < hend; ++h) {
        const float* row = fmap + h * W;
        for (int w = wstart; w < wend; ++w) {
            m = fmaxf(m, row[w]);
        }
    }
    out[idx] = empty ? 0.0f : m;
}

extern "C" void kernel_launch(void* const* d_in, const int* in_sizes, int n_in,
                              void* d_out, int out_size, void* d_ws, size_t ws_size,
                              hipStream_t stream) {
    const float* features = (const float*)d_in[0];
    const float* rois     = (const float*)d_in[1];
    float* out = (float*)d_out;

    int total = out_size;  // R * C * PH * PW
    int block = 256;
    int grid = (total + block - 1) / block;
    roipool_kernel<<<grid, block, 0, stream>>>(features, rois, out, total);
}